// Round 4
// baseline (3558.160 us; speedup 1.0000x reference)
//
#include <hip/hip_runtime.h>
#include <hip/hip_bf16.h>

// SimVQ forward for MI355X (gfx950).
// z:[32768,512] f32, embedding:[8192,512], proj weights 512x512.
// Outputs concatenated: quantized[16777216] f32, vq_loss[1] f32, idx[32768] (as f32).
//
// idx = argmax_n z_proj . c_n  (z-normalization is a positive per-row scale -> argmin-invariant)
//     = argmax_n  z . (Wz^T c_n) + bz . c_n
// Big GEMM done with split-bf16 (hi+lo) MFMA for fp32-grade accuracy.
// R3: loss via per-block partials (atomicAdd serialization fix).
// R4: k_scores block tile 128x256, wave tile 64x128 (4 MFMA per ds_read_b128,
//     -25% LDS bytes/FLOP, -50% barriers/FLOP). B-frags transient to cap VGPRs.

#define NQ    32768
#define NEMB  8192
#define DD    512

typedef __attribute__((ext_vector_type(8))) short bf16x8;
typedef __attribute__((ext_vector_type(4))) float f32x4;

__device__ __forceinline__ unsigned short f2bf_rne(float f) {
    unsigned u = __float_as_uint(f);
    unsigned r = u + 0x7FFFu + ((u >> 16) & 1u);
    return (unsigned short)(r >> 16);
}
__device__ __forceinline__ float bf2f(unsigned short b) {
    return __uint_as_float(((unsigned)b) << 16);
}

__device__ __forceinline__ void gload16(const void* g, void* l) {
    __builtin_amdgcn_global_load_lds(
        (const __attribute__((address_space(1))) unsigned int*)g,
        (__attribute__((address_space(3))) unsigned int*)l, 16, 0, 0);
}

// ---------------- Kernel 1: quant_codebook = embedding @ Wp^T + bp  (fp32) ----
// 128x64 tile, 256 threads, 8x4 per thread, float4 LDS reads.
__global__ __launch_bounds__(256) void k_qc_gemm(const float* __restrict__ emb,
                                                 const float* __restrict__ W,
                                                 const float* __restrict__ bias,
                                                 float* __restrict__ qc) {
    __shared__ float As[16][132];   // [k][m], pad to break pow2 stride
    __shared__ float Bs[16][68];    // [k][d]
    const int n0 = blockIdx.x * 128;
    const int d0 = blockIdx.y * 64;
    const int t  = threadIdx.x;
    const int tx = t & 15, ty = t >> 4;
    float acc[8][4] = {};
    for (int kb = 0; kb < DD; kb += 16) {
        for (int i = 0; i < 8; ++i) {          // A: 128x16 = 2048 elems
            int id = t + i * 256;
            int k = id & 15, m = id >> 4;
            As[k][m] = emb[(size_t)(n0 + m) * DD + kb + k];
        }
        for (int i = 0; i < 4; ++i) {          // B: 64x16 = 1024 elems
            int id = t + i * 256;
            int k = id & 15, m = id >> 4;
            Bs[k][m] = W[(size_t)(d0 + m) * DD + kb + k];
        }
        __syncthreads();
        for (int k = 0; k < 16; ++k) {
            float4 a0 = *(const float4*)&As[k][ty * 8];
            float4 a1 = *(const float4*)&As[k][ty * 8 + 4];
            float4 b  = *(const float4*)&Bs[k][tx * 4];
            const float av[8] = {a0.x, a0.y, a0.z, a0.w, a1.x, a1.y, a1.z, a1.w};
            const float bv[4] = {b.x, b.y, b.z, b.w};
            for (int i = 0; i < 8; ++i)
                for (int j = 0; j < 4; ++j) acc[i][j] = fmaf(av[i], bv[j], acc[i][j]);
        }
        __syncthreads();
    }
    float4 bv = *(const float4*)&bias[d0 + tx * 4];
    for (int i = 0; i < 8; ++i) {
        int n = n0 + ty * 8 + i;
        float4 o = {acc[i][0] + bv.x, acc[i][1] + bv.y, acc[i][2] + bv.z, acc[i][3] + bv.w};
        *(float4*)&qc[(size_t)n * DD + d0 + tx * 4] = o;
    }
}

// ---------------- Kernel 2: per-row 1/norm and t_n numerator -----------------
__global__ __launch_bounds__(256) void k_norm(const float* __restrict__ qc,
                                              const float* __restrict__ bz,
                                              float* __restrict__ rnorm,
                                              float* __restrict__ tvec) {
    const int n = blockIdx.x;
    const int t = threadIdx.x;
    float ss = 0.f, tb = 0.f;
    for (int d = t; d < DD; d += 256) {
        float v = qc[(size_t)n * DD + d];
        ss += v * v;
        tb += bz[d] * v;
    }
    for (int off = 32; off; off >>= 1) {
        ss += __shfl_down(ss, off);
        tb += __shfl_down(tb, off);
    }
    __shared__ float s1[4], s2[4];
    int wave = t >> 6, lane = t & 63;
    if (lane == 0) { s1[wave] = ss; s2[wave] = tb; }
    __syncthreads();
    if (t == 0) {
        ss = s1[0] + s1[1] + s1[2] + s1[3];
        tb = s2[0] + s2[1] + s2[2] + s2[3];
        float norm = sqrtf(ss);
        float rn = 1.f / fmaxf(norm, 1e-12f);
        rnorm[n] = rn;
        tvec[n] = tb * rn;  // bz . c_n (normalized)
    }
}

// ---------------- Kernel 3: e = (qc @ Wz) * rnorm, split to bf16 hi/lo -------
// e[n,k] = rnorm[n] * sum_d qc[n,d] * Wz[d,k].  128x64 tile, 8x4/thread.
__global__ __launch_bounds__(256) void k_e_gemm(const float* __restrict__ qc,
                                                const float* __restrict__ Wz,
                                                const float* __restrict__ rnorm,
                                                unsigned short* __restrict__ ehi,
                                                unsigned short* __restrict__ elo) {
    __shared__ float As[16][132];   // [d][n]
    __shared__ float Bs[16][68];    // [d][k]
    const int n0 = blockIdx.x * 128;
    const int k0 = blockIdx.y * 64;
    const int t  = threadIdx.x;
    const int tx = t & 15, ty = t >> 4;
    float acc[8][4] = {};
    for (int db = 0; db < DD; db += 16) {
        for (int i = 0; i < 8; ++i) {          // A: qc rows, k-inner
            int id = t + i * 256;
            int k = id & 15, m = id >> 4;
            As[k][m] = qc[(size_t)(n0 + m) * DD + db + k];
        }
        for (int i = 0; i < 4; ++i) {          // B: Wz[db+dk][k0+kc], row-major
            int id = t + i * 256;
            int kc = id & 63, dk = id >> 6;
            Bs[dk][kc] = Wz[(size_t)(db + dk) * DD + k0 + kc];
        }
        __syncthreads();
        for (int k = 0; k < 16; ++k) {
            float4 a0 = *(const float4*)&As[k][ty * 8];
            float4 a1 = *(const float4*)&As[k][ty * 8 + 4];
            float4 b  = *(const float4*)&Bs[k][tx * 4];
            const float av[8] = {a0.x, a0.y, a0.z, a0.w, a1.x, a1.y, a1.z, a1.w};
            const float bv[4] = {b.x, b.y, b.z, b.w};
            for (int i = 0; i < 8; ++i)
                for (int j = 0; j < 4; ++j) acc[i][j] = fmaf(av[i], bv[j], acc[i][j]);
        }
        __syncthreads();
    }
    for (int i = 0; i < 8; ++i) {
        int n = n0 + ty * 8 + i;
        float rn = rnorm[n];
        ushort4 hv, lv;
        float e0 = acc[i][0] * rn, e1 = acc[i][1] * rn, e2 = acc[i][2] * rn, e3 = acc[i][3] * rn;
        hv.x = f2bf_rne(e0); lv.x = f2bf_rne(e0 - bf2f(hv.x));
        hv.y = f2bf_rne(e1); lv.y = f2bf_rne(e1 - bf2f(hv.y));
        hv.z = f2bf_rne(e2); lv.z = f2bf_rne(e2 - bf2f(hv.z));
        hv.w = f2bf_rne(e3); lv.w = f2bf_rne(e3 - bf2f(hv.w));
        *(ushort4*)&ehi[(size_t)n * DD + k0 + tx * 4] = hv;
        *(ushort4*)&elo[(size_t)n * DD + k0 + tx * 4] = lv;
    }
}

// ---------------- Kernel 4: split z into bf16 hi/lo --------------------------
__global__ __launch_bounds__(256) void k_zsplit(const float* __restrict__ z,
                                                unsigned short* __restrict__ zhi,
                                                unsigned short* __restrict__ zlo) {
    const int n4 = (NQ * DD) / 4;
    const float4* z4 = (const float4*)z;
    ushort4* h4 = (ushort4*)zhi;
    ushort4* l4 = (ushort4*)zlo;
    for (int i = blockIdx.x * blockDim.x + threadIdx.x; i < n4; i += gridDim.x * blockDim.x) {
        float4 v = z4[i];
        ushort4 h, l;
        h.x = f2bf_rne(v.x); l.x = f2bf_rne(v.x - bf2f(h.x));
        h.y = f2bf_rne(v.y); l.y = f2bf_rne(v.y - bf2f(h.y));
        h.z = f2bf_rne(v.z); l.z = f2bf_rne(v.z - bf2f(h.z));
        h.w = f2bf_rne(v.w); l.w = f2bf_rne(v.w - bf2f(h.w));
        h4[i] = h;
        l4[i] = l;
    }
}

// ---------------- Kernel 5: scores + fused argmax ----------------------------
// score[q,n] = z_q . e_n + t_n, computed as hi*hi + hi*lo + lo*hi bf16 MFMA.
// Block tile 128(q) x 256(n), BK=32; 4 waves as 2x2, each wave owns 64x128.
// Per wave-iter: 24 ds_read_b128 feed 96 MFMAs (4 MFMA/read).
// LDS bank-conflict fix: k-group kg of row m stored at position kg^((m>>1)&3)
// (global_load_lds-compatible XOR swizzle; staging stays fully coalesced,
// every aligned 8-lane read group covers all 32 banks).
__global__ __launch_bounds__(256, 2) void k_scores(const unsigned short* __restrict__ Ah,
                                                   const unsigned short* __restrict__ Al,
                                                   const unsigned short* __restrict__ Bh,
                                                   const unsigned short* __restrict__ Bl,
                                                   const float* __restrict__ tvec,
                                                   unsigned long long* __restrict__ table) {
    __shared__ unsigned short sAh[128 * 32];
    __shared__ unsigned short sAl[128 * 32];
    __shared__ unsigned short sBh[256 * 32];
    __shared__ unsigned short sBl[256 * 32];

    const int t    = threadIdx.x;
    const int lane = t & 63;
    const int wave = t >> 6;
    const int wm   = wave >> 1;   // 0..1 : which 64 query rows
    const int wn   = wave & 1;    // 0..1 : which 128 code cols
    const int m0   = blockIdx.y * 128;
    const int n0   = blockIdx.x * 256;

    f32x4 acc[4][8];
    for (int i = 0; i < 4; ++i)
        for (int j = 0; j < 8; ++j) acc[i][j] = (f32x4){0.f, 0.f, 0.f, 0.f};

    // reader k-offset: position of k-group (lane>>4) in row (..+(lane&15)+16i)
    // = (lane>>4) ^ ((row>>1)&3); row bits 1..2 == lane bits 1..2.
    const int koff = (((lane >> 4) ^ ((lane >> 1) & 3)) << 3);

    for (int kb = 0; kb < DD; kb += 32) {
        // stage A: 128x32 (512 chunks), B: 256x32 (1024 chunks), hi+lo, w=16
        for (int r = 0; r < 2; ++r) {
            const int cbase = r * 256 + wave * 64;   // wave-uniform
            const int c = cbase + lane;              // chunk id 0..511
            const int m = c >> 2;
            const int kg = (c & 3) ^ ((m >> 1) & 3);
            const size_t ga = (size_t)(m0 + m) * DD + kb + kg * 8;
            gload16(Ah + ga, &sAh[cbase * 8]);
            gload16(Al + ga, &sAl[cbase * 8]);
        }
        for (int r = 0; r < 4; ++r) {
            const int cbase = r * 256 + wave * 64;   // wave-uniform
            const int c = cbase + lane;              // chunk id 0..1023
            const int m = c >> 2;
            const int kg = (c & 3) ^ ((m >> 1) & 3);
            const size_t gb = (size_t)(n0 + m) * DD + kb + kg * 8;
            gload16(Bh + gb, &sBh[cbase * 8]);
            gload16(Bl + gb, &sBl[cbase * 8]);
        }
        __syncthreads();

        bf16x8 afh[4], afl[4];
        const int ar = wm * 64 + (lane & 15);
        const int br = wn * 128 + (lane & 15);
        for (int i = 0; i < 4; ++i) {
            afh[i] = *(const bf16x8*)&sAh[(ar + i * 16) * 32 + koff];
            afl[i] = *(const bf16x8*)&sAl[(ar + i * 16) * 32 + koff];
        }
        for (int j = 0; j < 8; ++j) {
            bf16x8 bh = *(const bf16x8*)&sBh[(br + j * 16) * 32 + koff];
            bf16x8 bl = *(const bf16x8*)&sBl[(br + j * 16) * 32 + koff];
            for (int i = 0; i < 4; ++i) {
                acc[i][j] = __builtin_amdgcn_mfma_f32_16x16x32_bf16(afh[i], bh, acc[i][j], 0, 0, 0);
                acc[i][j] = __builtin_amdgcn_mfma_f32_16x16x32_bf16(afh[i], bl, acc[i][j], 0, 0, 0);
                acc[i][j] = __builtin_amdgcn_mfma_f32_16x16x32_bf16(afl[i], bh, acc[i][j], 0, 0, 0);
            }
        }
        __syncthreads();
    }

    // epilogue: add t_n, reduce row-wise argmax, merge via atomicMax
    const int col = lane & 15;
    const int g   = lane >> 4;
    float tc[8];
    for (int tn = 0; tn < 8; ++tn) tc[tn] = tvec[n0 + wn * 128 + tn * 16 + col];

    for (int tm = 0; tm < 4; ++tm) {
        for (int reg = 0; reg < 4; ++reg) {
            float best = -3.4e38f;
            int   bn   = 0x7FFFFFFF;
            for (int tn = 0; tn < 8; ++tn) {
                float v = acc[tm][tn][reg] + tc[tn];
                int n = n0 + wn * 128 + tn * 16 + col;
                if (v > best || (v == best && n < bn)) { best = v; bn = n; }
            }
            for (int off = 1; off < 16; off <<= 1) {
                float ov = __shfl_xor(best, off);
                int   on = __shfl_xor(bn, off);
                if (ov > best || (ov == best && on < bn)) { best = ov; bn = on; }
            }
            if (col == 0) {
                unsigned u = __float_as_uint(best);
                unsigned key = (u & 0x80000000u) ? ~u : (u | 0x80000000u);
                unsigned long long packed =
                    ((unsigned long long)key << 32) |
                    (unsigned long long)(0xFFFFFFFFu - (unsigned)bn);
                int q = m0 + wm * 64 + tm * 16 + g * 4 + reg;
                atomicMax(&table[q], packed);
            }
        }
    }
}

// ---------------- Kernel 6: gather quantized, per-block loss partial, idx ----
__global__ __launch_bounds__(128) void k_gather(const unsigned long long* __restrict__ table,
                                                const float* __restrict__ qc,
                                                const float* __restrict__ z,
                                                float* __restrict__ outq,
                                                float* __restrict__ partials,
                                                float* __restrict__ outidx) {
    const int q = blockIdx.x;
    const int t = threadIdx.x;  // 128 threads, one float4 each
    unsigned long long p = table[q];
    const int idx = (int)(0xFFFFFFFFu - (unsigned)(p & 0xFFFFFFFFull));
    const float4* src = (const float4*)(qc + (size_t)idx * DD);
    const float4* zs  = (const float4*)(z + (size_t)q * DD);
    float4* dst = (float4*)(outq + (size_t)q * DD);
    float4 a = src[t], b = zs[t];
    dst[t] = a;
    float dx = a.x - b.x, dy = a.y - b.y, dz = a.z - b.z, dw = a.w - b.w;
    float ss = dx * dx + dy * dy + dz * dz + dw * dw;
    for (int off = 32; off; off >>= 1) ss += __shfl_down(ss, off);
    __shared__ float sbuf[2];
    if ((t & 63) == 0) sbuf[t >> 6] = ss;
    __syncthreads();
    if (t == 0) {
        partials[q] = sbuf[0] + sbuf[1];
        outidx[q] = (float)idx;
    }
}

// ---------------- Kernel 7: final loss reduction -----------------------------
__global__ __launch_bounds__(1024) void k_loss(const float* __restrict__ partials,
                                               float* __restrict__ loss) {
    const int t = threadIdx.x;  // single block of 1024
    float s = 0.f;
    for (int i = t; i < NQ; i += 1024) s += partials[i];
    for (int off = 32; off; off >>= 1) s += __shfl_down(s, off);
    __shared__ float sbuf[16];
    if ((t & 63) == 0) sbuf[t >> 6] = s;
    __syncthreads();
    if (t == 0) {
        float tot = 0.f;
        for (int w = 0; w < 16; ++w) tot += sbuf[w];
        // vq_loss = (1 + beta) * mean((quantized - z)^2), beta = 0.25
        *loss = tot * (1.25f / 16777216.0f);
    }
}

extern "C" void kernel_launch(void* const* d_in, const int* in_sizes, int n_in,
                              void* d_out, int out_size, void* d_ws, size_t ws_size,
                              hipStream_t stream) {
    (void)in_sizes; (void)n_in; (void)out_size; (void)ws_size;
    const float* z   = (const float*)d_in[0];   // [32768,512]
    const float* emb = (const float*)d_in[1];   // [8192,512]
    const float* Wp  = (const float*)d_in[2];   // emb_proj_w [512,512]
    const float* bp  = (const float*)d_in[3];   // emb_proj_b [512]
    const float* Wz  = (const float*)d_in[4];   // z_proj_w [512,512]
    const float* bz  = (const float*)d_in[5];   // z_proj_b [512]
    // d_in[6] = l2_scale: positive scalar, argmin-invariant -> unused

    float* out = (float*)d_out;
    char* ws = (char*)d_ws;
    // ws layout (bytes):
    float* qc            = (float*)(ws + 0);           // 16,777,216
    float* rnorm         = (float*)(ws + 16777216);    //     32,768
    float* tvec          = (float*)(ws + 16809984);    //     32,768
    unsigned short* ehi  = (unsigned short*)(ws + 16842752);   // 8,388,608
    unsigned short* elo  = (unsigned short*)(ws + 25231360);   // 8,388,608
    unsigned short* zhi  = (unsigned short*)(ws + 33619968);   // 33,554,432
    unsigned short* zlo  = (unsigned short*)(ws + 67174400);   // 33,554,432
    unsigned long long* table = (unsigned long long*)(ws + 100728832); // 262,144
    // partials reuses zhi's region (dead after k_scores)
    float* partials      = (float*)(ws + 33619968);    //    131,072

    hipMemsetAsync(table, 0, (size_t)NQ * 8, stream);

    k_qc_gemm<<<dim3(NEMB / 128, DD / 64), 256, 0, stream>>>(emb, Wp, bp, qc);
    k_norm<<<NEMB, 256, 0, stream>>>(qc, bz, rnorm, tvec);
    k_e_gemm<<<dim3(NEMB / 128, DD / 64), 256, 0, stream>>>(qc, Wz, rnorm, ehi, elo);
    k_zsplit<<<4096, 256, 0, stream>>>(z, zhi, zlo);
    k_scores<<<dim3(NEMB / 256, NQ / 128), 256, 0, stream>>>(zhi, zlo, ehi, elo, tvec, table);
    k_gather<<<NQ, 128, 0, stream>>>(table, qc, z,
                                     out,
                                     partials,
                                     out + (size_t)NQ * DD + 1);
    k_loss<<<1, 1024, 0, stream>>>(partials, out + (size_t)NQ * DD);
}

// Round 5
// 1006.859 us; speedup vs baseline: 3.5339x; 3.5339x over previous
//
#include <hip/hip_runtime.h>
#include <hip/hip_bf16.h>

// SimVQ forward for MI355X (gfx950).
// z:[32768,512] f32, embedding:[8192,512], proj weights 512x512.
// Outputs concatenated: quantized[16777216] f32, vq_loss[1] f32, idx[32768] (as f32).
//
// idx = argmax_n z_proj . c_n  (z-normalization is a positive per-row scale -> argmin-invariant)
//     = argmax_n  z . (Wz^T c_n) + bz . c_n
// All GEMMs use split-bf16 (hi+lo) MFMA: x = hi + lo, x*y ~= hi*hi + hi*lo + lo*hi.
// R3: loss via per-block partials (atomicAdd serialization fix).
// R4 FAILED: 64x128 wave tile spilled accumulators to scratch (WRITE_SIZE 17.8 GB,
//     HBM 76%) -> 3430 us. 64x64 wave tile @ 76 VGPR + 64 AGPR is the register sweet
//     spot; k_scores reverted verbatim to the R3 848 us version.
// R5: the two small fp32 vector GEMMs (qc, e) converted to the same split-bf16
//     MFMA structure (~1.3e10 bf16-FLOP each, MFMA pipe) to recover ~150 us of
//     the 262 us non-k_scores time.

#define NQ    32768
#define NEMB  8192
#define DD    512

typedef __attribute__((ext_vector_type(8))) short bf16x8;
typedef __attribute__((ext_vector_type(4))) float f32x4;

__device__ __forceinline__ unsigned short f2bf_rne(float f) {
    unsigned u = __float_as_uint(f);
    unsigned r = u + 0x7FFFu + ((u >> 16) & 1u);
    return (unsigned short)(r >> 16);
}
__device__ __forceinline__ float bf2f(unsigned short b) {
    return __uint_as_float(((unsigned)b) << 16);
}

__device__ __forceinline__ void gload16(const void* g, void* l) {
    __builtin_amdgcn_global_load_lds(
        (const __attribute__((address_space(1))) unsigned int*)g,
        (__attribute__((address_space(3))) unsigned int*)l, 16, 0, 0);
}

// ---------------- generic fp32 -> bf16 hi/lo split ---------------------------
__global__ __launch_bounds__(256) void k_split(const float* __restrict__ src,
                                               unsigned short* __restrict__ hi,
                                               unsigned short* __restrict__ lo,
                                               int n4) {
    const float4* s4 = (const float4*)src;
    ushort4* h4 = (ushort4*)hi;
    ushort4* l4 = (ushort4*)lo;
    for (int i = blockIdx.x * blockDim.x + threadIdx.x; i < n4; i += gridDim.x * blockDim.x) {
        float4 v = s4[i];
        ushort4 h, l;
        h.x = f2bf_rne(v.x); l.x = f2bf_rne(v.x - bf2f(h.x));
        h.y = f2bf_rne(v.y); l.y = f2bf_rne(v.y - bf2f(h.y));
        h.z = f2bf_rne(v.z); l.z = f2bf_rne(v.z - bf2f(h.z));
        h.w = f2bf_rne(v.w); l.w = f2bf_rne(v.w - bf2f(h.w));
        h4[i] = h;
        l4[i] = l;
    }
}

// ---------------- transpose + split: T[k][d] = W[d][k] -----------------------
__global__ __launch_bounds__(256) void k_wtsplit(const float* __restrict__ W,
                                                 unsigned short* __restrict__ thi,
                                                 unsigned short* __restrict__ tlo) {
    __shared__ float t[32][33];
    const int bx = blockIdx.x * 32;  // output row block (k)
    const int by = blockIdx.y * 32;  // output col block (d)
    const int c = threadIdx.x & 31, r0 = threadIdx.x >> 5;
    for (int i = 0; i < 4; ++i) {
        int r = r0 + i * 8;
        t[r][c] = W[(size_t)(by + r) * DD + bx + c];
    }
    __syncthreads();
    for (int i = 0; i < 4; ++i) {
        int r = r0 + i * 8;
        float v = t[c][r];  // = W[by+c][bx+r]
        unsigned short h = f2bf_rne(v);
        thi[(size_t)(bx + r) * DD + by + c] = h;
        tlo[(size_t)(bx + r) * DD + by + c] = f2bf_rne(v - bf2f(h));
    }
}

// ---------------- MFMA GEMM core macro-structure -----------------------------
// Block tile 128(m) x 128(n), BK=32, 4 waves 2x2, wave tile 64x64.
// XOR bank swizzle: k-group kg of row m stored at kg^((m>>1)&3) (verified R2:
// 0 bank conflicts; staging stays fully coalesced under global_load_lds).

// Kernel: qc = emb @ Wp^T + bp  (writes fp32 qc AND its bf16 hi/lo split)
__global__ __launch_bounds__(256, 3) void k_qc_mfma(const unsigned short* __restrict__ Ah,
                                                    const unsigned short* __restrict__ Al,
                                                    const unsigned short* __restrict__ Bh,
                                                    const unsigned short* __restrict__ Bl,
                                                    const float* __restrict__ bias,
                                                    float* __restrict__ qc,
                                                    unsigned short* __restrict__ qhi,
                                                    unsigned short* __restrict__ qlo) {
    __shared__ unsigned short sAh[128 * 32];
    __shared__ unsigned short sAl[128 * 32];
    __shared__ unsigned short sBh[128 * 32];
    __shared__ unsigned short sBl[128 * 32];

    const int t    = threadIdx.x;
    const int lane = t & 63;
    const int wave = t >> 6;
    const int wm   = wave >> 1;
    const int wn   = wave & 1;
    const int m0   = blockIdx.y * 128;
    const int n0   = blockIdx.x * 128;

    f32x4 acc[4][4];
    for (int i = 0; i < 4; ++i)
        for (int j = 0; j < 4; ++j) acc[i][j] = (f32x4){0.f, 0.f, 0.f, 0.f};

    const int koff = (((lane >> 4) ^ ((lane >> 1) & 3)) << 3);

    for (int kb = 0; kb < DD; kb += 32) {
        for (int r = 0; r < 2; ++r) {
            const int cbase = r * 256 + wave * 64;
            const int c = cbase + lane;
            const int m = c >> 2;
            const int kg = (c & 3) ^ ((m >> 1) & 3);
            const size_t ga = (size_t)(m0 + m) * DD + kb + kg * 8;
            const size_t gb = (size_t)(n0 + m) * DD + kb + kg * 8;
            gload16(Ah + ga, &sAh[cbase * 8]);
            gload16(Al + ga, &sAl[cbase * 8]);
            gload16(Bh + gb, &sBh[cbase * 8]);
            gload16(Bl + gb, &sBl[cbase * 8]);
        }
        __syncthreads();

        bf16x8 afh[4], afl[4], bfh[4], bfl[4];
        const int ar = wm * 64 + (lane & 15);
        const int br = wn * 64 + (lane & 15);
        for (int i = 0; i < 4; ++i) {
            afh[i] = *(const bf16x8*)&sAh[(ar + i * 16) * 32 + koff];
            afl[i] = *(const bf16x8*)&sAl[(ar + i * 16) * 32 + koff];
            bfh[i] = *(const bf16x8*)&sBh[(br + i * 16) * 32 + koff];
            bfl[i] = *(const bf16x8*)&sBl[(br + i * 16) * 32 + koff];
        }
        for (int i = 0; i < 4; ++i)
            for (int j = 0; j < 4; ++j) {
                acc[i][j] = __builtin_amdgcn_mfma_f32_16x16x32_bf16(afh[i], bfh[j], acc[i][j], 0, 0, 0);
                acc[i][j] = __builtin_amdgcn_mfma_f32_16x16x32_bf16(afh[i], bfl[j], acc[i][j], 0, 0, 0);
                acc[i][j] = __builtin_amdgcn_mfma_f32_16x16x32_bf16(afl[i], bfh[j], acc[i][j], 0, 0, 0);
            }
        __syncthreads();
    }

    // epilogue: C/D layout col=lane&15, row=(lane>>4)*4+reg
    const int colb = lane & 15;
    const int g    = lane >> 4;
    float bcol[4];
    for (int tn = 0; tn < 4; ++tn) bcol[tn] = bias[n0 + wn * 64 + tn * 16 + colb];
    for (int tm = 0; tm < 4; ++tm) {
        for (int reg = 0; reg < 4; ++reg) {
            int row = m0 + wm * 64 + tm * 16 + g * 4 + reg;
            for (int tn = 0; tn < 4; ++tn) {
                int col = n0 + wn * 64 + tn * 16 + colb;
                float v = acc[tm][tn][reg] + bcol[tn];
                size_t o = (size_t)row * DD + col;
                qc[o] = v;
                unsigned short h = f2bf_rne(v);
                qhi[o] = h;
                qlo[o] = f2bf_rne(v - bf2f(h));
            }
        }
    }
}

// Kernel: e = rnorm .* (qc @ Wz)  via transposed-split Wz; writes bf16 hi/lo.
__global__ __launch_bounds__(256, 3) void k_e_mfma(const unsigned short* __restrict__ Ah,
                                                   const unsigned short* __restrict__ Al,
                                                   const unsigned short* __restrict__ Bh,
                                                   const unsigned short* __restrict__ Bl,
                                                   const float* __restrict__ rnorm,
                                                   unsigned short* __restrict__ ehi,
                                                   unsigned short* __restrict__ elo) {
    __shared__ unsigned short sAh[128 * 32];
    __shared__ unsigned short sAl[128 * 32];
    __shared__ unsigned short sBh[128 * 32];
    __shared__ unsigned short sBl[128 * 32];

    const int t    = threadIdx.x;
    const int lane = t & 63;
    const int wave = t >> 6;
    const int wm   = wave >> 1;
    const int wn   = wave & 1;
    const int m0   = blockIdx.y * 128;
    const int n0   = blockIdx.x * 128;

    f32x4 acc[4][4];
    for (int i = 0; i < 4; ++i)
        for (int j = 0; j < 4; ++j) acc[i][j] = (f32x4){0.f, 0.f, 0.f, 0.f};

    const int koff = (((lane >> 4) ^ ((lane >> 1) & 3)) << 3);

    for (int kb = 0; kb < DD; kb += 32) {
        for (int r = 0; r < 2; ++r) {
            const int cbase = r * 256 + wave * 64;
            const int c = cbase + lane;
            const int m = c >> 2;
            const int kg = (c & 3) ^ ((m >> 1) & 3);
            const size_t ga = (size_t)(m0 + m) * DD + kb + kg * 8;
            const size_t gb = (size_t)(n0 + m) * DD + kb + kg * 8;
            gload16(Ah + ga, &sAh[cbase * 8]);
            gload16(Al + ga, &sAl[cbase * 8]);
            gload16(Bh + gb, &sBh[cbase * 8]);
            gload16(Bl + gb, &sBl[cbase * 8]);
        }
        __syncthreads();

        bf16x8 afh[4], afl[4], bfh[4], bfl[4];
        const int ar = wm * 64 + (lane & 15);
        const int br = wn * 64 + (lane & 15);
        for (int i = 0; i < 4; ++i) {
            afh[i] = *(const bf16x8*)&sAh[(ar + i * 16) * 32 + koff];
            afl[i] = *(const bf16x8*)&sAl[(ar + i * 16) * 32 + koff];
            bfh[i] = *(const bf16x8*)&sBh[(br + i * 16) * 32 + koff];
            bfl[i] = *(const bf16x8*)&sBl[(br + i * 16) * 32 + koff];
        }
        for (int i = 0; i < 4; ++i)
            for (int j = 0; j < 4; ++j) {
                acc[i][j] = __builtin_amdgcn_mfma_f32_16x16x32_bf16(afh[i], bfh[j], acc[i][j], 0, 0, 0);
                acc[i][j] = __builtin_amdgcn_mfma_f32_16x16x32_bf16(afh[i], bfl[j], acc[i][j], 0, 0, 0);
                acc[i][j] = __builtin_amdgcn_mfma_f32_16x16x32_bf16(afl[i], bfh[j], acc[i][j], 0, 0, 0);
            }
        __syncthreads();
    }

    const int colb = lane & 15;
    const int g    = lane >> 4;
    for (int tm = 0; tm < 4; ++tm) {
        const int rbase = m0 + wm * 64 + tm * 16 + g * 4;
        float4 rn4 = *(const float4*)&rnorm[rbase];
        const float rnv[4] = {rn4.x, rn4.y, rn4.z, rn4.w};
        for (int reg = 0; reg < 4; ++reg) {
            int row = rbase + reg;
            for (int tn = 0; tn < 4; ++tn) {
                int col = n0 + wn * 64 + tn * 16 + colb;
                float v = acc[tm][tn][reg] * rnv[reg];
                size_t o = (size_t)row * DD + col;
                unsigned short h = f2bf_rne(v);
                ehi[o] = h;
                elo[o] = f2bf_rne(v - bf2f(h));
            }
        }
    }
}

// ---------------- per-row 1/norm and t_n numerator ---------------------------
__global__ __launch_bounds__(256) void k_norm(const float* __restrict__ qc,
                                              const float* __restrict__ bz,
                                              float* __restrict__ rnorm,
                                              float* __restrict__ tvec) {
    const int n = blockIdx.x;
    const int t = threadIdx.x;
    float ss = 0.f, tb = 0.f;
    for (int d = t; d < DD; d += 256) {
        float v = qc[(size_t)n * DD + d];
        ss += v * v;
        tb += bz[d] * v;
    }
    for (int off = 32; off; off >>= 1) {
        ss += __shfl_down(ss, off);
        tb += __shfl_down(tb, off);
    }
    __shared__ float s1[4], s2[4];
    int wave = t >> 6, lane = t & 63;
    if (lane == 0) { s1[wave] = ss; s2[wave] = tb; }
    __syncthreads();
    if (t == 0) {
        ss = s1[0] + s1[1] + s1[2] + s1[3];
        tb = s2[0] + s2[1] + s2[2] + s2[3];
        float norm = sqrtf(ss);
        float rn = 1.f / fmaxf(norm, 1e-12f);
        rnorm[n] = rn;
        tvec[n] = tb * rn;  // bz . c_n (normalized)
    }
}

// ---------------- scores + fused argmax (R3 verbatim, 848 us) ----------------
__global__ __launch_bounds__(256, 3) void k_scores(const unsigned short* __restrict__ Ah,
                                                   const unsigned short* __restrict__ Al,
                                                   const unsigned short* __restrict__ Bh,
                                                   const unsigned short* __restrict__ Bl,
                                                   const float* __restrict__ tvec,
                                                   unsigned long long* __restrict__ table) {
    __shared__ unsigned short sAh[128 * 32];
    __shared__ unsigned short sAl[128 * 32];
    __shared__ unsigned short sBh[128 * 32];
    __shared__ unsigned short sBl[128 * 32];

    const int t    = threadIdx.x;
    const int lane = t & 63;
    const int wave = t >> 6;
    const int wm   = wave >> 1;
    const int wn   = wave & 1;
    const int m0   = blockIdx.y * 128;
    const int n0   = blockIdx.x * 128;

    f32x4 acc[4][4];
    for (int i = 0; i < 4; ++i)
        for (int j = 0; j < 4; ++j) acc[i][j] = (f32x4){0.f, 0.f, 0.f, 0.f};

    const int koff = (((lane >> 4) ^ ((lane >> 1) & 3)) << 3);

    for (int kb = 0; kb < DD; kb += 32) {
        for (int r = 0; r < 2; ++r) {
            const int cbase = r * 256 + wave * 64;
            const int c = cbase + lane;
            const int m = c >> 2;
            const int kg = (c & 3) ^ ((m >> 1) & 3);
            const size_t ga = (size_t)(m0 + m) * DD + kb + kg * 8;
            const size_t gb = (size_t)(n0 + m) * DD + kb + kg * 8;
            gload16(Ah + ga, &sAh[cbase * 8]);
            gload16(Al + ga, &sAl[cbase * 8]);
            gload16(Bh + gb, &sBh[cbase * 8]);
            gload16(Bl + gb, &sBl[cbase * 8]);
        }
        __syncthreads();

        bf16x8 afh[4], afl[4], bfh[4], bfl[4];
        const int ar = wm * 64 + (lane & 15);
        const int br = wn * 64 + (lane & 15);
        for (int i = 0; i < 4; ++i) {
            afh[i] = *(const bf16x8*)&sAh[(ar + i * 16) * 32 + koff];
            afl[i] = *(const bf16x8*)&sAl[(ar + i * 16) * 32 + koff];
            bfh[i] = *(const bf16x8*)&sBh[(br + i * 16) * 32 + koff];
            bfl[i] = *(const bf16x8*)&sBl[(br + i * 16) * 32 + koff];
        }
        for (int i = 0; i < 4; ++i)
            for (int j = 0; j < 4; ++j) {
                acc[i][j] = __builtin_amdgcn_mfma_f32_16x16x32_bf16(afh[i], bfh[j], acc[i][j], 0, 0, 0);
                acc[i][j] = __builtin_amdgcn_mfma_f32_16x16x32_bf16(afh[i], bfl[j], acc[i][j], 0, 0, 0);
                acc[i][j] = __builtin_amdgcn_mfma_f32_16x16x32_bf16(afl[i], bfh[j], acc[i][j], 0, 0, 0);
            }
        __syncthreads();
    }

    const int col = lane & 15;
    const int g   = lane >> 4;
    float tc[4];
    for (int tn = 0; tn < 4; ++tn) tc[tn] = tvec[n0 + wn * 64 + tn * 16 + col];

    for (int tm = 0; tm < 4; ++tm) {
        for (int reg = 0; reg < 4; ++reg) {
            float best = -3.4e38f;
            int   bn   = 0x7FFFFFFF;
            for (int tn = 0; tn < 4; ++tn) {
                float v = acc[tm][tn][reg] + tc[tn];
                int n = n0 + wn * 64 + tn * 16 + col;
                if (v > best || (v == best && n < bn)) { best = v; bn = n; }
            }
            for (int off = 1; off < 16; off <<= 1) {
                float ov = __shfl_xor(best, off);
                int   on = __shfl_xor(bn, off);
                if (ov > best || (ov == best && on < bn)) { best = ov; bn = on; }
            }
            if (col == 0) {
                unsigned u = __float_as_uint(best);
                unsigned key = (u & 0x80000000u) ? ~u : (u | 0x80000000u);
                unsigned long long packed =
                    ((unsigned long long)key << 32) |
                    (unsigned long long)(0xFFFFFFFFu - (unsigned)bn);
                int q = m0 + wm * 64 + tm * 16 + g * 4 + reg;
                atomicMax(&table[q], packed);
            }
        }
    }
}

// ---------------- gather quantized, per-block loss partial, idx --------------
__global__ __launch_bounds__(128) void k_gather(const unsigned long long* __restrict__ table,
                                                const float* __restrict__ qc,
                                                const float* __restrict__ z,
                                                float* __restrict__ outq,
                                                float* __restrict__ partials,
                                                float* __restrict__ outidx) {
    const int q = blockIdx.x;
    const int t = threadIdx.x;  // 128 threads, one float4 each
    unsigned long long p = table[q];
    const int idx = (int)(0xFFFFFFFFu - (unsigned)(p & 0xFFFFFFFFull));
    const float4* src = (const float4*)(qc + (size_t)idx * DD);
    const float4* zs  = (const float4*)(z + (size_t)q * DD);
    float4* dst = (float4*)(outq + (size_t)q * DD);
    float4 a = src[t], b = zs[t];
    dst[t] = a;
    float dx = a.x - b.x, dy = a.y - b.y, dz = a.z - b.z, dw = a.w - b.w;
    float ss = dx * dx + dy * dy + dz * dz + dw * dw;
    for (int off = 32; off; off >>= 1) ss += __shfl_down(ss, off);
    __shared__ float sbuf[2];
    if ((t & 63) == 0) sbuf[t >> 6] = ss;
    __syncthreads();
    if (t == 0) {
        partials[q] = sbuf[0] + sbuf[1];
        outidx[q] = (float)idx;
    }
}

// ---------------- final loss reduction ---------------------------------------
__global__ __launch_bounds__(1024) void k_loss(const float* __restrict__ partials,
                                               float* __restrict__ loss) {
    const int t = threadIdx.x;  // single block of 1024
    float s = 0.f;
    for (int i = t; i < NQ; i += 1024) s += partials[i];
    for (int off = 32; off; off >>= 1) s += __shfl_down(s, off);
    __shared__ float sbuf[16];
    if ((t & 63) == 0) sbuf[t >> 6] = s;
    __syncthreads();
    if (t == 0) {
        float tot = 0.f;
        for (int w = 0; w < 16; ++w) tot += sbuf[w];
        // vq_loss = (1 + beta) * mean((quantized - z)^2), beta = 0.25
        *loss = tot * (1.25f / 16777216.0f);
    }
}

extern "C" void kernel_launch(void* const* d_in, const int* in_sizes, int n_in,
                              void* d_out, int out_size, void* d_ws, size_t ws_size,
                              hipStream_t stream) {
    (void)in_sizes; (void)n_in; (void)out_size; (void)ws_size;
    const float* z   = (const float*)d_in[0];   // [32768,512]
    const float* emb = (const float*)d_in[1];   // [8192,512]
    const float* Wp  = (const float*)d_in[2];   // emb_proj_w [512,512]
    const float* bp  = (const float*)d_in[3];   // emb_proj_b [512]
    const float* Wz  = (const float*)d_in[4];   // z_proj_w [512,512]
    const float* bz  = (const float*)d_in[5];   // z_proj_b [512]
    // d_in[6] = l2_scale: positive scalar, argmin-invariant -> unused

    float* out = (float*)d_out;
    char* ws = (char*)d_ws;
    // ws layout (bytes), total 100,991 KB -- matches R3's proven footprint:
    float* qc            = (float*)(ws + 0);           // 16,777,216
    float* rnorm         = (float*)(ws + 16777216);    //     32,768
    float* tvec          = (float*)(ws + 16809984);    //     32,768
    unsigned short* ehi  = (unsigned short*)(ws + 16842752);   // 8,388,608
    unsigned short* elo  = (unsigned short*)(ws + 25231360);   // 8,388,608
    unsigned short* zhi  = (unsigned short*)(ws + 33619968);   // 33,554,432
    unsigned short* zlo  = (unsigned short*)(ws + 67174400);   // 33,554,432
    unsigned long long* table = (unsigned long long*)(ws + 100728832); // 262,144

    // Phase-overlapped aliases (all dead before their region is overwritten):
    // inside zhi region (overwritten by k_split(z) AFTER k_e_mfma):
    unsigned short* embhi = (unsigned short*)(ws + 33619968);             // 8 MB
    unsigned short* emblo = (unsigned short*)(ws + 33619968 + 8388608);   // 8 MB
    unsigned short* qchi  = (unsigned short*)(ws + 33619968 + 16777216);  // 8 MB
    unsigned short* qclo  = (unsigned short*)(ws + 33619968 + 25165824);  // 8 MB
    // inside zlo region (overwritten by k_split(z) AFTER k_e_mfma):
    unsigned short* wphi  = (unsigned short*)(ws + 67174400);             // 512 KB
    unsigned short* wplo  = (unsigned short*)(ws + 67174400 + 524288);    // 512 KB
    unsigned short* wzthi = (unsigned short*)(ws + 67174400 + 1048576);   // 512 KB
    unsigned short* wztlo = (unsigned short*)(ws + 67174400 + 1572864);   // 512 KB
    // partials reuses zhi head (dead after k_scores)
    float* partials      = (float*)(ws + 33619968);    //    131,072

    hipMemsetAsync(table, 0, (size_t)NQ * 8, stream);

    k_split<<<1024, 256, 0, stream>>>(emb, embhi, emblo, NEMB * DD / 4);
    k_split<<<256, 256, 0, stream>>>(Wp, wphi, wplo, DD * DD / 4);
    k_wtsplit<<<dim3(16, 16), 256, 0, stream>>>(Wz, wzthi, wztlo);

    k_qc_mfma<<<dim3(DD / 128, NEMB / 128), 256, 0, stream>>>(embhi, emblo, wphi, wplo,
                                                              bp, qc, qchi, qclo);
    k_norm<<<NEMB, 256, 0, stream>>>(qc, bz, rnorm, tvec);
    k_e_mfma<<<dim3(DD / 128, NEMB / 128), 256, 0, stream>>>(qchi, qclo, wzthi, wztlo,
                                                             rnorm, ehi, elo);
    k_split<<<4096, 256, 0, stream>>>(z, zhi, zlo, NQ * DD / 4);

    k_scores<<<dim3(NEMB / 128, NQ / 128), 256, 0, stream>>>(zhi, zlo, ehi, elo, tvec, table);
    k_gather<<<NQ, 128, 0, stream>>>(table, qc, z,
                                     out,
                                     partials,
                                     out + (size_t)NQ * DD + 1);
    k_loss<<<1, 1024, 0, stream>>>(partials, out + (size_t)NQ * DD);
}